// Round 4
// baseline (913.772 us; speedup 1.0000x reference)
//
#include <hip/hip_runtime.h>
#include <hip/hip_bf16.h>
#include <stdint.h>

// Problem: B=8, L=1024, C=1024, H=16, HD=64, window +/-64 (WS=128).
// Round-4 model: inputs float32, OUTPUT float32 (the "(bf16" in the harness
// assert is literal template text; inputs were proven f32 via the round-3
// detector agreeing bit-exactly with round-2's hard-coded f32 path).
// Intermediates (q/k/v/attn) are bf16 in ws (~22 MiB).

typedef __attribute__((ext_vector_type(8))) short bf16x8;
typedef __attribute__((ext_vector_type(4))) float f32x4;

__device__ inline unsigned short f2b(float f) {
    __hip_bfloat16 h = __float2bfloat16(f);
    return *reinterpret_cast<unsigned short*>(&h);
}
__device__ inline float b2f(unsigned short u) {
    __hip_bfloat16 h;
    *reinterpret_cast<unsigned short*>(&h) = u;
    return __bfloat162float(h);
}

// dual-dtype load of 8 consecutive elements -> 8 bf16 regs
__device__ inline void ld8(const float* __restrict__ pf,
                           const unsigned short* __restrict__ pb,
                           size_t eidx, int isf32, unsigned short* t) {
    if (isf32) {
        float4 a = *(const float4*)(pf + eidx);
        float4 b = *(const float4*)(pf + eidx + 4);
        t[0] = f2b(a.x); t[1] = f2b(a.y); t[2] = f2b(a.z); t[3] = f2b(a.w);
        t[4] = f2b(b.x); t[5] = f2b(b.y); t[6] = f2b(b.z); t[7] = f2b(b.w);
    } else {
        *(uint4*)t = *(const uint4*)(pb + eidx);
    }
}
__device__ inline float ldscalar(const float* __restrict__ pf,
                                 const unsigned short* __restrict__ pb,
                                 size_t eidx, int isf32) {
    return isf32 ? pf[eidx] : b2f(pb[eidx]);
}

// ---- dtype detector: count bf16 NaN/Inf exponent patterns in first 256K u16 ----
// f32 data: low-u16 halves have random mantissa bits -> ~512 hits. bf16 N(0,1): 0.
__global__ void __launch_bounds__(256) detect_dtype(
    const unsigned short* __restrict__ xs, int* __restrict__ flag) {
    __shared__ int part[256];
    int tid = threadIdx.x;
    int cnt = 0;
    for (int i = tid; i < 262144; i += 256) {
        unsigned e = (xs[i] >> 7) & 0xFFu;
        cnt += (e == 0xFFu) ? 1 : 0;
    }
    part[tid] = cnt;
    __syncthreads();
    if (tid == 0) {
        int s = 0;
        for (int i = 0; i < 256; ++i) s += part[i];
        *flag = (s > 8) ? 1 : 0;   // 1 = inputs are f32, 0 = inputs are bf16
    }
}

#define BM 128
#define BN 128
#define BK 32
#define LP 40  // LDS pitch (bf16 elems) = 32 + 8 pad

// QKV GEMM for one head pair hp: output column strips
//   q cols [hp*128,+128), k cols [1024+hp*128,+128), v cols [2048+hp*128,+128)
// C[M,N] = x[M,K] * W[N,K]^T + b ; scatter into pair-scratch Q/K/V [16,1024,64] bf16
__global__ void __launch_bounds__(256) gemm_qkv_pair(
    const float* __restrict__ xf, const unsigned short* __restrict__ xb,
    const float* __restrict__ wf, const unsigned short* __restrict__ wb,
    const float* __restrict__ bf_, const unsigned short* __restrict__ bb_,
    const int* __restrict__ flagp, int hp,
    unsigned short* __restrict__ Qo, unsigned short* __restrict__ Ko,
    unsigned short* __restrict__ Vo)
{
    const int K = 1024;
    int isf = *flagp;
    int sec = blockIdx.x;                 // 0=q strip, 1=k strip, 2=v strip
    int nrow0 = sec * 1024 + hp * 128;    // in_proj_w row base for this strip
    int m0 = blockIdx.y * BM;
    int tid = threadIdx.x;
    int wave = tid >> 6, lane = tid & 63;
    int lm = lane & 15, quad = lane >> 4;
    int mblk = (wave & 1) * 64, nblk = (wave >> 1) * 64;

    __shared__ unsigned short As[BM * LP];
    __shared__ unsigned short Bs[BN * LP];

    int srow = tid >> 2;          // 0..63
    int skc  = (tid & 3) * 8;     // 0,8,16,24

    f32x4 acc[4][4];
#pragma unroll
    for (int i = 0; i < 4; ++i)
#pragma unroll
        for (int j = 0; j < 4; ++j)
            acc[i][j] = (f32x4){0.f, 0.f, 0.f, 0.f};

    for (int k0 = 0; k0 < K; k0 += BK) {
        unsigned short a0[8], a1[8], b0[8], b1[8];
        ld8(xf, xb, (size_t)(m0 + srow) * K + k0 + skc, isf, a0);
        ld8(xf, xb, (size_t)(m0 + srow + 64) * K + k0 + skc, isf, a1);
        ld8(wf, wb, (size_t)(nrow0 + srow) * K + k0 + skc, isf, b0);
        ld8(wf, wb, (size_t)(nrow0 + srow + 64) * K + k0 + skc, isf, b1);
        __syncthreads();
        *(uint4*)(As + srow * LP + skc) = *(uint4*)a0;
        *(uint4*)(As + (srow + 64) * LP + skc) = *(uint4*)a1;
        *(uint4*)(Bs + srow * LP + skc) = *(uint4*)b0;
        *(uint4*)(Bs + (srow + 64) * LP + skc) = *(uint4*)b1;
        __syncthreads();
        bf16x8 af[4], bfr[4];
#pragma unroll
        for (int i = 0; i < 4; ++i)
            af[i] = *(const bf16x8*)(As + (mblk + i * 16 + lm) * LP + quad * 8);
#pragma unroll
        for (int j = 0; j < 4; ++j)
            bfr[j] = *(const bf16x8*)(Bs + (nblk + j * 16 + lm) * LP + quad * 8);
#pragma unroll
        for (int i = 0; i < 4; ++i)
#pragma unroll
            for (int j = 0; j < 4; ++j)
                acc[i][j] = __builtin_amdgcn_mfma_f32_16x16x32_bf16(af[i], bfr[j], acc[i][j], 0, 0, 0);
    }

    unsigned short* dst = (sec == 0) ? Qo : (sec == 1) ? Ko : Vo;
#pragma unroll
    for (int j = 0; j < 4; ++j) {
        int c = nblk + j * 16 + lm;        // 0..127 within strip
        float bv = ldscalar(bf_, bb_, (size_t)(nrow0 + c), isf);
        int h2 = c >> 6, d = c & 63;       // head-in-pair, dim
#pragma unroll
        for (int i = 0; i < 4; ++i) {
#pragma unroll
            for (int r = 0; r < 4; ++r) {
                int m = m0 + mblk + i * 16 + quad * 4 + r;
                int bb2 = m >> 10, sl = m & 1023;
                size_t idx = ((size_t)((bb2 * 2 + h2) * 1024 + sl)) * 64 + d;
                dst[idx] = f2b(acc[i][j][r] + bv);
            }
        }
    }
}

// Local attention for one head pair. One block per (b, h2, 64-row q tile):
// 16 bhl * 16 qt = 256 blocks. Window keys [q0-64, q0+128) = 192 rows.
__global__ void __launch_bounds__(256) attn_pair(
    const unsigned short* __restrict__ Qg,   // [16,1024,64] bf16 pair scratch
    const unsigned short* __restrict__ Kg,
    const unsigned short* __restrict__ Vg,
    unsigned short* __restrict__ Og,         // [8,1024,1024] bf16 attn buffer
    int hp)
{
    const int KP = 72;    // K-tile pitch: 64 + 8 pad
    const int VP = 200;   // Vt / P pitch: 192 + 8 pad
    __shared__ unsigned short Ks[192 * KP];  // reused as P after barrier
    __shared__ unsigned short Vt[64 * VP];

    int tid = threadIdx.x;
    int wave = tid >> 6, lane = tid & 63;
    int lm = lane & 15, quad = lane >> 4;

    int bhl = blockIdx.x >> 4;       // 0..15 = b*2 + h2
    int qt = blockIdx.x & 15;
    int q0 = qt * 64;
    int b = bhl >> 1, h2 = bhl & 1;
    int h = hp * 2 + h2;
    const unsigned short* Qbh = Qg + (size_t)bhl * 1024 * 64;
    const unsigned short* Kbh = Kg + (size_t)bhl * 1024 * 64;
    const unsigned short* Vbh = Vg + (size_t)bhl * 1024 * 64;
    int j0 = q0 - 64;

#pragma unroll
    for (int it = 0; it < 6; ++it) {
        int id = it * 256 + tid;     // 0..1535
        int r = id >> 3;             // key row 0..191
        int c = (id & 7) * 8;        // d offset 0..56
        int j = j0 + r;
        uint4 kv, vv;
        kv.x = kv.y = kv.z = kv.w = 0;
        vv = kv;
        if (j >= 0 && j < 1024) {
            kv = *(const uint4*)(Kbh + (size_t)j * 64 + c);
            vv = *(const uint4*)(Vbh + (size_t)j * 64 + c);
        }
        *(uint4*)(Ks + r * KP + c) = kv;
        unsigned short tmp[8];
        *(uint4*)tmp = vv;
#pragma unroll
        for (int e = 0; e < 8; ++e) Vt[(c + e) * VP + r] = tmp[e];
    }
    __syncthreads();

    int qrow = q0 + wave * 16;
    bf16x8 qf0 = *(const bf16x8*)(Qbh + (size_t)(qrow + lm) * 64 + quad * 8);
    bf16x8 qf1 = *(const bf16x8*)(Qbh + (size_t)(qrow + lm) * 64 + 32 + quad * 8);

    f32x4 sc[12];
#pragma unroll
    for (int kt = 0; kt < 12; ++kt) {
        f32x4 a = (f32x4){0.f, 0.f, 0.f, 0.f};
        bf16x8 k0f = *(const bf16x8*)(Ks + (kt * 16 + lm) * KP + quad * 8);
        bf16x8 k1f = *(const bf16x8*)(Ks + (kt * 16 + lm) * KP + 32 + quad * 8);
        a = __builtin_amdgcn_mfma_f32_16x16x32_bf16(qf0, k0f, a, 0, 0, 0);
        a = __builtin_amdgcn_mfma_f32_16x16x32_bf16(qf1, k1f, a, 0, 0, 0);
        sc[kt] = a;
    }

    float mx[4] = {-3e38f, -3e38f, -3e38f, -3e38f};
#pragma unroll
    for (int kt = 0; kt < 12; ++kt) {
        int jg = j0 + kt * 16 + lm;
#pragma unroll
        for (int r = 0; r < 4; ++r) {
            int irow = q0 + wave * 16 + quad * 4 + r;
            int diff = irow - jg;
            bool ok = (jg >= 0) && (jg < 1024) && (diff <= 64) && (diff >= -64);
            float s = ok ? sc[kt][r] * 0.125f : -30000.0f;
            sc[kt][r] = s;
            mx[r] = fmaxf(mx[r], s);
        }
    }
#pragma unroll
    for (int off = 1; off <= 8; off <<= 1)
#pragma unroll
        for (int r = 0; r < 4; ++r)
            mx[r] = fmaxf(mx[r], __shfl_xor(mx[r], off, 64));

    float sum[4] = {0.f, 0.f, 0.f, 0.f};
#pragma unroll
    for (int kt = 0; kt < 12; ++kt)
#pragma unroll
        for (int r = 0; r < 4; ++r) {
            float p = __expf(sc[kt][r] - mx[r]);
            sc[kt][r] = p;
            sum[r] += p;
        }
#pragma unroll
    for (int off = 1; off <= 8; off <<= 1)
#pragma unroll
        for (int r = 0; r < 4; ++r)
            sum[r] += __shfl_xor(sum[r], off, 64);

    __syncthreads();  // all waves done reading Ks as the K tile
    unsigned short* Pb = Ks + wave * 3200;  // per-wave P buffer [16][VP]
#pragma unroll
    for (int kt = 0; kt < 12; ++kt)
#pragma unroll
        for (int r = 0; r < 4; ++r)
            Pb[(quad * 4 + r) * VP + kt * 16 + lm] = f2b(sc[kt][r]);
    __syncthreads();

    f32x4 o[4];
#pragma unroll
    for (int n = 0; n < 4; ++n) o[n] = (f32x4){0.f, 0.f, 0.f, 0.f};
#pragma unroll
    for (int jc = 0; jc < 6; ++jc) {
        bf16x8 pf = *(const bf16x8*)(Pb + lm * VP + jc * 32 + quad * 8);
#pragma unroll
        for (int n = 0; n < 4; ++n) {
            bf16x8 vf = *(const bf16x8*)(Vt + (n * 16 + lm) * VP + jc * 32 + quad * 8);
            o[n] = __builtin_amdgcn_mfma_f32_16x16x32_bf16(pf, vf, o[n], 0, 0, 0);
        }
    }

    float inv[4];
#pragma unroll
    for (int r = 0; r < 4; ++r) inv[r] = 1.0f / sum[r];
#pragma unroll
    for (int n = 0; n < 4; ++n)
#pragma unroll
        for (int r = 0; r < 4; ++r) {
            int orow = q0 + wave * 16 + quad * 4 + r;
            size_t oidx = ((size_t)(b * 1024 + orow)) * 1024 + h * 64 + n * 16 + lm;
            Og[oidx] = f2b(o[n][r] * inv[r]);
        }
}

// out[M,N] = attn[M,K](bf16) * W2[N,K]^T + b2 -> FLOAT32 output
__global__ void __launch_bounds__(256) gemm_proj(
    const unsigned short* __restrict__ A,  // attn [8192,1024] bf16 (ws)
    const float* __restrict__ wf, const unsigned short* __restrict__ wb,
    const float* __restrict__ bf_, const unsigned short* __restrict__ bb_,
    const int* __restrict__ flagp,
    float* __restrict__ Out)               // [8192,1024] f32
{
    const int K = 1024;
    int isf = *flagp;
    int n0 = blockIdx.x * BN;
    int m0 = blockIdx.y * BM;
    int tid = threadIdx.x;
    int wave = tid >> 6, lane = tid & 63;
    int lm = lane & 15, quad = lane >> 4;
    int mblk = (wave & 1) * 64, nblk = (wave >> 1) * 64;

    __shared__ unsigned short As[BM * LP];
    __shared__ unsigned short Bs[BN * LP];

    int srow = tid >> 2;
    int skc  = (tid & 3) * 8;

    f32x4 acc[4][4];
#pragma unroll
    for (int i = 0; i < 4; ++i)
#pragma unroll
        for (int j = 0; j < 4; ++j)
            acc[i][j] = (f32x4){0.f, 0.f, 0.f, 0.f};

    for (int k0 = 0; k0 < K; k0 += BK) {
        uint4 a0 = *(const uint4*)(A + (size_t)(m0 + srow) * K + k0 + skc);
        uint4 a1 = *(const uint4*)(A + (size_t)(m0 + srow + 64) * K + k0 + skc);
        unsigned short b0[8], b1[8];
        ld8(wf, wb, (size_t)(n0 + srow) * K + k0 + skc, isf, b0);
        ld8(wf, wb, (size_t)(n0 + srow + 64) * K + k0 + skc, isf, b1);
        __syncthreads();
        *(uint4*)(As + srow * LP + skc) = a0;
        *(uint4*)(As + (srow + 64) * LP + skc) = a1;
        *(uint4*)(Bs + srow * LP + skc) = *(uint4*)b0;
        *(uint4*)(Bs + (srow + 64) * LP + skc) = *(uint4*)b1;
        __syncthreads();
        bf16x8 af[4], bfr[4];
#pragma unroll
        for (int i = 0; i < 4; ++i)
            af[i] = *(const bf16x8*)(As + (mblk + i * 16 + lm) * LP + quad * 8);
#pragma unroll
        for (int j = 0; j < 4; ++j)
            bfr[j] = *(const bf16x8*)(Bs + (nblk + j * 16 + lm) * LP + quad * 8);
#pragma unroll
        for (int i = 0; i < 4; ++i)
#pragma unroll
            for (int j = 0; j < 4; ++j)
                acc[i][j] = __builtin_amdgcn_mfma_f32_16x16x32_bf16(af[i], bfr[j], acc[i][j], 0, 0, 0);
    }

#pragma unroll
    for (int j = 0; j < 4; ++j) {
        int n = n0 + nblk + j * 16 + lm;
        float bv = ldscalar(bf_, bb_, (size_t)n, isf);
#pragma unroll
        for (int i = 0; i < 4; ++i) {
#pragma unroll
            for (int r = 0; r < 4; ++r) {
                int m = m0 + mblk + i * 16 + quad * 4 + r;
                Out[(size_t)m * 1024 + n] = acc[i][j][r] + bv;
            }
        }
    }
}

extern "C" void kernel_launch(void* const* d_in, const int* in_sizes, int n_in,
                              void* d_out, int out_size, void* d_ws, size_t ws_size,
                              hipStream_t stream) {
    const float* xf  = (const float*)d_in[0];
    const float* w1f = (const float*)d_in[1];
    const float* b1f = (const float*)d_in[2];
    const float* w2f = (const float*)d_in[3];
    const float* b2f = (const float*)d_in[4];
    const unsigned short* xb  = (const unsigned short*)d_in[0];
    const unsigned short* w1b = (const unsigned short*)d_in[1];
    const unsigned short* b1b = (const unsigned short*)d_in[2];
    const unsigned short* w2b = (const unsigned short*)d_in[3];
    const unsigned short* b2b = (const unsigned short*)d_in[4];
    float* out = (float*)d_out;  // [8,1024,1024] f32

    // ws layout (~22 MiB):
    //  [0,64)    : dtype flag (int)
    //  [64,+16Mi): attn buffer [8,1024,1024] bf16
    //  then 3 x 2 MiB per-pair q/k/v scratch [16,1024,64] bf16
    char* ws = (char*)d_ws;
    int* flag = (int*)ws;
    unsigned short* attn = (unsigned short*)(ws + 64);
    const size_t ATT = (size_t)8 * 1024 * 1024 * 2;      // 16 MiB
    const size_t PSZ = (size_t)16 * 1024 * 64 * 2;       // 2 MiB per tensor
    unsigned short* q = (unsigned short*)(ws + 64 + ATT);
    unsigned short* k = (unsigned short*)(ws + 64 + ATT + PSZ);
    unsigned short* v = (unsigned short*)(ws + 64 + ATT + 2 * PSZ);

    dim3 blk(256);
    detect_dtype<<<1, blk, 0, stream>>>(xb, flag);
    for (int hp = 0; hp < 8; ++hp) {
        gemm_qkv_pair<<<dim3(3, 64), blk, 0, stream>>>(
            xf, xb, w1f, w1b, b1f, b1b, flag, hp, q, k, v);
        attn_pair<<<dim3(256), blk, 0, stream>>>(q, k, v, attn, hp);
    }
    gemm_proj<<<dim3(8, 64), blk, 0, stream>>>(attn, w2f, w2b, b2f, b2b, flag, out);
}

// Round 5
// 292.673 us; speedup vs baseline: 3.1222x; 3.1222x over previous
//
#include <hip/hip_runtime.h>
#include <hip/hip_bf16.h>
#include <stdint.h>

// Problem: B=8, L=1024, C=1024, H=16, HD=64, window +/-64 (WS=128).
// Confirmed model (round 4 passed): inputs f32, output f32, bf16 intermediates OK.
// Round-5: drop detect_dtype (was 233us on 1 CU), re-merge per-pair split into
// single-shot gemm_qkv / attn_local / gemm_proj (round-2 structure, f32 out).

typedef __attribute__((ext_vector_type(8))) short bf16x8;
typedef __attribute__((ext_vector_type(4))) float f32x4;

__device__ inline unsigned short f2b(float f) {
    __hip_bfloat16 h = __float2bfloat16(f);
    return *reinterpret_cast<unsigned short*>(&h);
}

// load 8 consecutive f32, round to 8 bf16 in registers
__device__ inline void ld8f32(const float* __restrict__ src, unsigned short* t) {
    float4 a = *(const float4*)src;
    float4 b = *(const float4*)(src + 4);
    t[0] = f2b(a.x); t[1] = f2b(a.y); t[2] = f2b(a.z); t[3] = f2b(a.w);
    t[4] = f2b(b.x); t[5] = f2b(b.y); t[6] = f2b(b.z); t[7] = f2b(b.w);
}

#define BM 128
#define BN 128
#define BK 32
#define LP 40  // LDS pitch (bf16 elems) = 32 + 8 pad

// C[M,N] = x[M,K] * W[N,K]^T + b ; scatter into Q/K/V [8,16,1024,64] bf16
__global__ void __launch_bounds__(256) gemm_qkv(
    const float* __restrict__ A,     // x [8192,1024] f32
    const float* __restrict__ W,     // in_proj_w [3072,1024] f32
    const float* __restrict__ bias,  // [3072] f32
    unsigned short* __restrict__ Qo,
    unsigned short* __restrict__ Ko,
    unsigned short* __restrict__ Vo)
{
    const int K = 1024;
    int n0 = blockIdx.x * BN;
    int m0 = blockIdx.y * BM;
    int tid = threadIdx.x;
    int wave = tid >> 6, lane = tid & 63;
    int lm = lane & 15, quad = lane >> 4;
    int mblk = (wave & 1) * 64, nblk = (wave >> 1) * 64;

    __shared__ unsigned short As[BM * LP];
    __shared__ unsigned short Bs[BN * LP];

    int srow = tid >> 2;          // 0..63
    int skc  = (tid & 3) * 8;     // 0,8,16,24

    f32x4 acc[4][4];
#pragma unroll
    for (int i = 0; i < 4; ++i)
#pragma unroll
        for (int j = 0; j < 4; ++j)
            acc[i][j] = (f32x4){0.f, 0.f, 0.f, 0.f};

    for (int k0 = 0; k0 < K; k0 += BK) {
        unsigned short a0[8], a1[8], b0[8], b1[8];
        ld8f32(A + (size_t)(m0 + srow) * K + k0 + skc, a0);
        ld8f32(A + (size_t)(m0 + srow + 64) * K + k0 + skc, a1);
        ld8f32(W + (size_t)(n0 + srow) * K + k0 + skc, b0);
        ld8f32(W + (size_t)(n0 + srow + 64) * K + k0 + skc, b1);
        __syncthreads();
        *(uint4*)(As + srow * LP + skc) = *(uint4*)a0;
        *(uint4*)(As + (srow + 64) * LP + skc) = *(uint4*)a1;
        *(uint4*)(Bs + srow * LP + skc) = *(uint4*)b0;
        *(uint4*)(Bs + (srow + 64) * LP + skc) = *(uint4*)b1;
        __syncthreads();
        bf16x8 af[4], bfr[4];
#pragma unroll
        for (int i = 0; i < 4; ++i)
            af[i] = *(const bf16x8*)(As + (mblk + i * 16 + lm) * LP + quad * 8);
#pragma unroll
        for (int j = 0; j < 4; ++j)
            bfr[j] = *(const bf16x8*)(Bs + (nblk + j * 16 + lm) * LP + quad * 8);
#pragma unroll
        for (int i = 0; i < 4; ++i)
#pragma unroll
            for (int j = 0; j < 4; ++j)
                acc[i][j] = __builtin_amdgcn_mfma_f32_16x16x32_bf16(af[i], bfr[j], acc[i][j], 0, 0, 0);
    }

#pragma unroll
    for (int j = 0; j < 4; ++j) {
        int n = n0 + nblk + j * 16 + lm;
        float bv = bias[n];
        int sec = n >> 10, rem = n & 1023;
        int h = rem >> 6, d = rem & 63;
        unsigned short* dst = (sec == 0) ? Qo : (sec == 1) ? Ko : Vo;
#pragma unroll
        for (int i = 0; i < 4; ++i) {
#pragma unroll
            for (int r = 0; r < 4; ++r) {
                int m = m0 + mblk + i * 16 + quad * 4 + r;
                int bb = m >> 10, sl = m & 1023;
                size_t idx = ((size_t)((bb * 16 + h) * 1024 + sl)) * 64 + d;
                dst[idx] = f2b(acc[i][j][r] + bv);
            }
        }
    }
}

// Local attention: one block per (b, h, 64-row q tile); 2048 blocks.
// Window |i-j|<=64 -> keys [q0-64, q0+128) = 192 rows.
__global__ void __launch_bounds__(256) attn_local(
    const unsigned short* __restrict__ Qg,   // [B*H,1024,64] bf16
    const unsigned short* __restrict__ Kg,
    const unsigned short* __restrict__ Vg,
    unsigned short* __restrict__ Og)         // [8,1024,1024] bf16 attn buffer
{
    const int KP = 72;    // K-tile pitch: 64 + 8 pad
    const int VP = 200;   // Vt / P pitch: 192 + 8 pad
    __shared__ unsigned short Ks[192 * KP];  // reused as P after barrier
    __shared__ unsigned short Vt[64 * VP];

    int tid = threadIdx.x;
    int wave = tid >> 6, lane = tid & 63;
    int lm = lane & 15, quad = lane >> 4;

    int bh = blockIdx.x >> 4;        // b*16 + h
    int qt = blockIdx.x & 15;
    int q0 = qt * 64;
    int b = bh >> 4, h = bh & 15;
    const unsigned short* Qbh = Qg + (size_t)bh * 1024 * 64;
    const unsigned short* Kbh = Kg + (size_t)bh * 1024 * 64;
    const unsigned short* Vbh = Vg + (size_t)bh * 1024 * 64;
    int j0 = q0 - 64;

#pragma unroll
    for (int it = 0; it < 6; ++it) {
        int id = it * 256 + tid;     // 0..1535
        int r = id >> 3;             // key row 0..191
        int c = (id & 7) * 8;        // d offset 0..56
        int j = j0 + r;
        uint4 kv, vv;
        kv.x = kv.y = kv.z = kv.w = 0;
        vv = kv;
        if (j >= 0 && j < 1024) {
            kv = *(const uint4*)(Kbh + (size_t)j * 64 + c);
            vv = *(const uint4*)(Vbh + (size_t)j * 64 + c);
        }
        *(uint4*)(Ks + r * KP + c) = kv;
        unsigned short tmp[8];
        *(uint4*)tmp = vv;
#pragma unroll
        for (int e = 0; e < 8; ++e) Vt[(c + e) * VP + r] = tmp[e];
    }
    __syncthreads();

    int qrow = q0 + wave * 16;
    bf16x8 qf0 = *(const bf16x8*)(Qbh + (size_t)(qrow + lm) * 64 + quad * 8);
    bf16x8 qf1 = *(const bf16x8*)(Qbh + (size_t)(qrow + lm) * 64 + 32 + quad * 8);

    f32x4 sc[12];
#pragma unroll
    for (int kt = 0; kt < 12; ++kt) {
        f32x4 a = (f32x4){0.f, 0.f, 0.f, 0.f};
        bf16x8 k0f = *(const bf16x8*)(Ks + (kt * 16 + lm) * KP + quad * 8);
        bf16x8 k1f = *(const bf16x8*)(Ks + (kt * 16 + lm) * KP + 32 + quad * 8);
        a = __builtin_amdgcn_mfma_f32_16x16x32_bf16(qf0, k0f, a, 0, 0, 0);
        a = __builtin_amdgcn_mfma_f32_16x16x32_bf16(qf1, k1f, a, 0, 0, 0);
        sc[kt] = a;
    }

    float mx[4] = {-3e38f, -3e38f, -3e38f, -3e38f};
#pragma unroll
    for (int kt = 0; kt < 12; ++kt) {
        int jg = j0 + kt * 16 + lm;
#pragma unroll
        for (int r = 0; r < 4; ++r) {
            int irow = q0 + wave * 16 + quad * 4 + r;
            int diff = irow - jg;
            bool ok = (jg >= 0) && (jg < 1024) && (diff <= 64) && (diff >= -64);
            float s = ok ? sc[kt][r] * 0.125f : -30000.0f;
            sc[kt][r] = s;
            mx[r] = fmaxf(mx[r], s);
        }
    }
#pragma unroll
    for (int off = 1; off <= 8; off <<= 1)
#pragma unroll
        for (int r = 0; r < 4; ++r)
            mx[r] = fmaxf(mx[r], __shfl_xor(mx[r], off, 64));

    float sum[4] = {0.f, 0.f, 0.f, 0.f};
#pragma unroll
    for (int kt = 0; kt < 12; ++kt)
#pragma unroll
        for (int r = 0; r < 4; ++r) {
            float p = __expf(sc[kt][r] - mx[r]);
            sc[kt][r] = p;
            sum[r] += p;
        }
#pragma unroll
    for (int off = 1; off <= 8; off <<= 1)
#pragma unroll
        for (int r = 0; r < 4; ++r)
            sum[r] += __shfl_xor(sum[r], off, 64);

    __syncthreads();  // all waves done reading Ks as the K tile
    unsigned short* Pb = Ks + wave * 3200;  // per-wave P buffer [16][VP]
#pragma unroll
    for (int kt = 0; kt < 12; ++kt)
#pragma unroll
        for (int r = 0; r < 4; ++r)
            Pb[(quad * 4 + r) * VP + kt * 16 + lm] = f2b(sc[kt][r]);
    __syncthreads();

    f32x4 o[4];
#pragma unroll
    for (int n = 0; n < 4; ++n) o[n] = (f32x4){0.f, 0.f, 0.f, 0.f};
#pragma unroll
    for (int jc = 0; jc < 6; ++jc) {
        bf16x8 pf = *(const bf16x8*)(Pb + lm * VP + jc * 32 + quad * 8);
#pragma unroll
        for (int n = 0; n < 4; ++n) {
            bf16x8 vf = *(const bf16x8*)(Vt + (n * 16 + lm) * VP + jc * 32 + quad * 8);
            o[n] = __builtin_amdgcn_mfma_f32_16x16x32_bf16(pf, vf, o[n], 0, 0, 0);
        }
    }

    float inv[4];
#pragma unroll
    for (int r = 0; r < 4; ++r) inv[r] = 1.0f / sum[r];
#pragma unroll
    for (int n = 0; n < 4; ++n)
#pragma unroll
        for (int r = 0; r < 4; ++r) {
            int orow = q0 + wave * 16 + quad * 4 + r;
            size_t oidx = ((size_t)(b * 1024 + orow)) * 1024 + h * 64 + n * 16 + lm;
            Og[oidx] = f2b(o[n][r] * inv[r]);
        }
}

// out[M,N] = attn[M,K](bf16) * W2[N,K](f32->bf16)^T + b2 -> f32 output
__global__ void __launch_bounds__(256) gemm_proj(
    const unsigned short* __restrict__ A,  // attn [8192,1024] bf16 (ws)
    const float* __restrict__ W,           // out_w [1024,1024] f32
    const float* __restrict__ bias,        // [1024] f32
    float* __restrict__ Out)               // [8192,1024] f32
{
    const int K = 1024;
    int n0 = blockIdx.x * BN;
    int m0 = blockIdx.y * BM;
    int tid = threadIdx.x;
    int wave = tid >> 6, lane = tid & 63;
    int lm = lane & 15, quad = lane >> 4;
    int mblk = (wave & 1) * 64, nblk = (wave >> 1) * 64;

    __shared__ unsigned short As[BM * LP];
    __shared__ unsigned short Bs[BN * LP];

    int srow = tid >> 2;
    int skc  = (tid & 3) * 8;

    f32x4 acc[4][4];
#pragma unroll
    for (int i = 0; i < 4; ++i)
#pragma unroll
        for (int j = 0; j < 4; ++j)
            acc[i][j] = (f32x4){0.f, 0.f, 0.f, 0.f};

    for (int k0 = 0; k0 < K; k0 += BK) {
        uint4 a0 = *(const uint4*)(A + (size_t)(m0 + srow) * K + k0 + skc);
        uint4 a1 = *(const uint4*)(A + (size_t)(m0 + srow + 64) * K + k0 + skc);
        unsigned short b0[8], b1[8];
        ld8f32(W + (size_t)(n0 + srow) * K + k0 + skc, b0);
        ld8f32(W + (size_t)(n0 + srow + 64) * K + k0 + skc, b1);
        __syncthreads();
        *(uint4*)(As + srow * LP + skc) = a0;
        *(uint4*)(As + (srow + 64) * LP + skc) = a1;
        *(uint4*)(Bs + srow * LP + skc) = *(uint4*)b0;
        *(uint4*)(Bs + (srow + 64) * LP + skc) = *(uint4*)b1;
        __syncthreads();
        bf16x8 af[4], bfr[4];
#pragma unroll
        for (int i = 0; i < 4; ++i)
            af[i] = *(const bf16x8*)(As + (mblk + i * 16 + lm) * LP + quad * 8);
#pragma unroll
        for (int j = 0; j < 4; ++j)
            bfr[j] = *(const bf16x8*)(Bs + (nblk + j * 16 + lm) * LP + quad * 8);
#pragma unroll
        for (int i = 0; i < 4; ++i)
#pragma unroll
            for (int j = 0; j < 4; ++j)
                acc[i][j] = __builtin_amdgcn_mfma_f32_16x16x32_bf16(af[i], bfr[j], acc[i][j], 0, 0, 0);
    }

#pragma unroll
    for (int j = 0; j < 4; ++j) {
        int n = n0 + nblk + j * 16 + lm;
        float bv = bias[n];
#pragma unroll
        for (int i = 0; i < 4; ++i) {
#pragma unroll
            for (int r = 0; r < 4; ++r) {
                int m = m0 + mblk + i * 16 + quad * 4 + r;
                Out[(size_t)m * 1024 + n] = acc[i][j][r] + bv;
            }
        }
    }
}

extern "C" void kernel_launch(void* const* d_in, const int* in_sizes, int n_in,
                              void* d_out, int out_size, void* d_ws, size_t ws_size,
                              hipStream_t stream) {
    const float* x  = (const float*)d_in[0];  // [8,1024,1024] f32
    const float* w1 = (const float*)d_in[1];  // [3072,1024] f32
    const float* b1 = (const float*)d_in[2];  // [3072] f32
    const float* w2 = (const float*)d_in[3];  // [1024,1024] f32
    const float* b2 = (const float*)d_in[4];  // [1024] f32
    float* out = (float*)d_out;               // [8,1024,1024] f32

    // ws: q/k/v [8,16,1024,64] bf16 (16 MiB each) + attn [8192,1024] bf16 (16 MiB)
    char* ws = (char*)d_ws;
    const size_t SZ = (size_t)8 * 16 * 1024 * 64 * 2;
    unsigned short* q    = (unsigned short*)(ws);
    unsigned short* k    = (unsigned short*)(ws + SZ);
    unsigned short* v    = (unsigned short*)(ws + 2 * SZ);
    unsigned short* attn = (unsigned short*)(ws + 3 * SZ);

    dim3 blk(256);
    gemm_qkv<<<dim3(24, 64), blk, 0, stream>>>(x, w1, b1, q, k, v);
    attn_local<<<dim3(2048), blk, 0, stream>>>(q, k, v, attn);
    gemm_proj<<<dim3(8, 64), blk, 0, stream>>>(attn, w2, b2, out);
}

// Round 6
// 225.888 us; speedup vs baseline: 4.0453x; 1.2957x over previous
//
#include <hip/hip_runtime.h>
#include <hip/hip_bf16.h>
#include <stdint.h>

// Problem: B=8, L=1024, C=1024, H=16, HD=64, window +/-64 (WS=128).
// Model (confirmed r4/r5): inputs f32, output f32, bf16 intermediates OK.
// Round-6: m97-style GEMMs — pre-cast operands to bf16, stage via
// global_load_lds width=16 (no ds_write), XOR-swizzled LDS tile to kill
// bank conflicts. v parked in d_out's first 16 MiB; attn overlays xb.

typedef __attribute__((ext_vector_type(8))) short bf16x8;
typedef __attribute__((ext_vector_type(4))) float f32x4;

__device__ inline unsigned short f2b(float f) {
    __hip_bfloat16 h = __float2bfloat16(f);
    return *reinterpret_cast<unsigned short*>(&h);
}

// async global->LDS, 16B per lane; LDS dest = wave-uniform base + lane*16
__device__ inline void gld16(const unsigned short* g, unsigned short* l) {
    __builtin_amdgcn_global_load_lds(
        (const __attribute__((address_space(1))) void*)g,
        (__attribute__((address_space(3))) void*)l, 16, 0, 0);
}

#define BM 128
#define BN 128
#define BK 32

// ---- cast f32 inputs to bf16 side buffers (x, in_proj_w, out_w) ----
__global__ void __launch_bounds__(256) cast_inputs(
    const float4* __restrict__ x, const float4* __restrict__ w1,
    const float4* __restrict__ w2,
    uint2* __restrict__ xb, uint2* __restrict__ w1b, uint2* __restrict__ w2b)
{
    const int N0 = 2097152, N1 = 786432, N2 = 262144;  // float4 counts
    int stride = gridDim.x * blockDim.x;
    for (int i = blockIdx.x * blockDim.x + threadIdx.x; i < N0 + N1 + N2; i += stride) {
        const float4* src; uint2* dst; int idx;
        if (i < N0)            { src = x;  dst = xb;  idx = i; }
        else if (i < N0 + N1)  { src = w1; dst = w1b; idx = i - N0; }
        else                   { src = w2; dst = w2b; idx = i - N0 - N1; }
        float4 f = src[idx];
        unsigned short t[4] = {f2b(f.x), f2b(f.y), f2b(f.z), f2b(f.w)};
        dst[idx] = *(uint2*)t;
    }
}

// ---- QKV GEMM: C[M,N] = xb[M,K] * w1b[N,K]^T + b1 ; scatter to Q/K/V ----
// LDS tile 128x32 bf16, unpadded, XOR-swizzled: logical col-chunk c of row r
// stored at chunk position c ^ ((r>>1)&3). Swizzle applied on the GLOBAL
// source address (per-lane), so the DMA's lane-ordered LDS write is dense.
__global__ void __launch_bounds__(256) gemm_qkv(
    const unsigned short* __restrict__ A,   // xb [8192,1024] bf16
    const unsigned short* __restrict__ W,   // w1b [3072,1024] bf16
    const float* __restrict__ bias,         // [3072] f32
    unsigned short* __restrict__ Qo,
    unsigned short* __restrict__ Ko,
    unsigned short* __restrict__ Vo)
{
    const int K = 1024;
    int n0 = blockIdx.x * BN;
    int m0 = blockIdx.y * BM;
    int tid = threadIdx.x;
    int wave = tid >> 6, lane = tid & 63;
    int lm = lane & 15, quad = lane >> 4;
    int mblk = (wave & 1) * 64, nblk = (wave >> 1) * 64;

    __shared__ unsigned short As[BM * BK];  // 8 KiB
    __shared__ unsigned short Bs[BN * BK];  // 8 KiB

    // staging geometry: wave handles chunks c0, c0+1 of each tile
    // chunk c = rows [c*16, c*16+16); lane -> row c*16 + (lane>>2),
    // swizzled col-chunk = (lane&3) ^ ((lane>>3)&3)
    int c0 = wave * 2;
    int lrow = c0 * 16 + (lane >> 2);
    int gcc = (lane & 3) ^ ((lane >> 3) & 3);
    const unsigned short* ga0 = A + (size_t)(m0 + lrow) * K + gcc * 8;
    const unsigned short* ga1 = A + (size_t)(m0 + lrow + 16) * K + gcc * 8;
    const unsigned short* gb0 = W + (size_t)(n0 + lrow) * K + gcc * 8;
    const unsigned short* gb1 = W + (size_t)(n0 + lrow + 16) * K + gcc * 8;
    unsigned short* la0 = As + c0 * 512;
    unsigned short* la1 = As + c0 * 512 + 512;
    unsigned short* lb0 = Bs + c0 * 512;
    unsigned short* lb1 = Bs + c0 * 512 + 512;

    // fragment-read lane offset: row = tile16 + lm, stored chunk = quad ^ ((lm>>1)&3)
    int sa = (lm >> 1) & 3;
    int fro = lm * 32 + ((quad ^ sa) << 3);

    f32x4 acc[4][4];
#pragma unroll
    for (int i = 0; i < 4; ++i)
#pragma unroll
        for (int j = 0; j < 4; ++j)
            acc[i][j] = (f32x4){0.f, 0.f, 0.f, 0.f};

    for (int k0 = 0; k0 < K; k0 += BK) {
        __syncthreads();                 // prev iter's ds_reads done
        gld16(ga0 + k0, la0);
        gld16(ga1 + k0, la1);
        gld16(gb0 + k0, lb0);
        gld16(gb1 + k0, lb1);
        __syncthreads();                 // DMA drained (vmcnt before barrier)
        bf16x8 af[4], bfr[4];
#pragma unroll
        for (int i = 0; i < 4; ++i)
            af[i] = *(const bf16x8*)(As + (mblk + i * 16) * 32 + fro);
#pragma unroll
        for (int j = 0; j < 4; ++j)
            bfr[j] = *(const bf16x8*)(Bs + (nblk + j * 16) * 32 + fro);
#pragma unroll
        for (int i = 0; i < 4; ++i)
#pragma unroll
            for (int j = 0; j < 4; ++j)
                acc[i][j] = __builtin_amdgcn_mfma_f32_16x16x32_bf16(af[i], bfr[j], acc[i][j], 0, 0, 0);
    }

#pragma unroll
    for (int j = 0; j < 4; ++j) {
        int n = n0 + nblk + j * 16 + lm;
        float bv = bias[n];
        int sec = n >> 10, rem = n & 1023;
        int h = rem >> 6, d = rem & 63;
        unsigned short* dst = (sec == 0) ? Qo : (sec == 1) ? Ko : Vo;
#pragma unroll
        for (int i = 0; i < 4; ++i) {
#pragma unroll
            for (int r = 0; r < 4; ++r) {
                int m = m0 + mblk + i * 16 + quad * 4 + r;
                int bb = m >> 10, sl = m & 1023;
                size_t idx = ((size_t)((bb * 16 + h) * 1024 + sl)) * 64 + d;
                dst[idx] = f2b(acc[i][j][r] + bv);
            }
        }
    }
}

// ---- local attention (unchanged from round 5) ----
__global__ void __launch_bounds__(256) attn_local(
    const unsigned short* __restrict__ Qg,   // [B*H,1024,64] bf16
    const unsigned short* __restrict__ Kg,
    const unsigned short* __restrict__ Vg,
    unsigned short* __restrict__ Og)         // [8192,1024] bf16
{
    const int KP = 72;
    const int VP = 200;
    __shared__ unsigned short Ks[192 * KP];
    __shared__ unsigned short Vt[64 * VP];

    int tid = threadIdx.x;
    int wave = tid >> 6, lane = tid & 63;
    int lm = lane & 15, quad = lane >> 4;

    int bh = blockIdx.x >> 4;
    int qt = blockIdx.x & 15;
    int q0 = qt * 64;
    int b = bh >> 4, h = bh & 15;
    const unsigned short* Qbh = Qg + (size_t)bh * 1024 * 64;
    const unsigned short* Kbh = Kg + (size_t)bh * 1024 * 64;
    const unsigned short* Vbh = Vg + (size_t)bh * 1024 * 64;
    int j0 = q0 - 64;

#pragma unroll
    for (int it = 0; it < 6; ++it) {
        int id = it * 256 + tid;
        int r = id >> 3;
        int c = (id & 7) * 8;
        int j = j0 + r;
        uint4 kv, vv;
        kv.x = kv.y = kv.z = kv.w = 0;
        vv = kv;
        if (j >= 0 && j < 1024) {
            kv = *(const uint4*)(Kbh + (size_t)j * 64 + c);
            vv = *(const uint4*)(Vbh + (size_t)j * 64 + c);
        }
        *(uint4*)(Ks + r * KP + c) = kv;
        unsigned short tmp[8];
        *(uint4*)tmp = vv;
#pragma unroll
        for (int e = 0; e < 8; ++e) Vt[(c + e) * VP + r] = tmp[e];
    }
    __syncthreads();

    int qrow = q0 + wave * 16;
    bf16x8 qf0 = *(const bf16x8*)(Qbh + (size_t)(qrow + lm) * 64 + quad * 8);
    bf16x8 qf1 = *(const bf16x8*)(Qbh + (size_t)(qrow + lm) * 64 + 32 + quad * 8);

    f32x4 sc[12];
#pragma unroll
    for (int kt = 0; kt < 12; ++kt) {
        f32x4 a = (f32x4){0.f, 0.f, 0.f, 0.f};
        bf16x8 k0f = *(const bf16x8*)(Ks + (kt * 16 + lm) * KP + quad * 8);
        bf16x8 k1f = *(const bf16x8*)(Ks + (kt * 16 + lm) * KP + 32 + quad * 8);
        a = __builtin_amdgcn_mfma_f32_16x16x32_bf16(qf0, k0f, a, 0, 0, 0);
        a = __builtin_amdgcn_mfma_f32_16x16x32_bf16(qf1, k1f, a, 0, 0, 0);
        sc[kt] = a;
    }

    float mx[4] = {-3e38f, -3e38f, -3e38f, -3e38f};
#pragma unroll
    for (int kt = 0; kt < 12; ++kt) {
        int jg = j0 + kt * 16 + lm;
#pragma unroll
        for (int r = 0; r < 4; ++r) {
            int irow = q0 + wave * 16 + quad * 4 + r;
            int diff = irow - jg;
            bool ok = (jg >= 0) && (jg < 1024) && (diff <= 64) && (diff >= -64);
            float s = ok ? sc[kt][r] * 0.125f : -30000.0f;
            sc[kt][r] = s;
            mx[r] = fmaxf(mx[r], s);
        }
    }
#pragma unroll
    for (int off = 1; off <= 8; off <<= 1)
#pragma unroll
        for (int r = 0; r < 4; ++r)
            mx[r] = fmaxf(mx[r], __shfl_xor(mx[r], off, 64));

    float sum[4] = {0.f, 0.f, 0.f, 0.f};
#pragma unroll
    for (int kt = 0; kt < 12; ++kt)
#pragma unroll
        for (int r = 0; r < 4; ++r) {
            float p = __expf(sc[kt][r] - mx[r]);
            sc[kt][r] = p;
            sum[r] += p;
        }
#pragma unroll
    for (int off = 1; off <= 8; off <<= 1)
#pragma unroll
        for (int r = 0; r < 4; ++r)
            sum[r] += __shfl_xor(sum[r], off, 64);

    __syncthreads();
    unsigned short* Pb = Ks + wave * 3200;
#pragma unroll
    for (int kt = 0; kt < 12; ++kt)
#pragma unroll
        for (int r = 0; r < 4; ++r)
            Pb[(quad * 4 + r) * VP + kt * 16 + lm] = f2b(sc[kt][r]);
    __syncthreads();

    f32x4 o[4];
#pragma unroll
    for (int n = 0; n < 4; ++n) o[n] = (f32x4){0.f, 0.f, 0.f, 0.f};
#pragma unroll
    for (int jc = 0; jc < 6; ++jc) {
        bf16x8 pf = *(const bf16x8*)(Pb + lm * VP + jc * 32 + quad * 8);
#pragma unroll
        for (int n = 0; n < 4; ++n) {
            bf16x8 vf = *(const bf16x8*)(Vt + (n * 16 + lm) * VP + jc * 32 + quad * 8);
            o[n] = __builtin_amdgcn_mfma_f32_16x16x32_bf16(pf, vf, o[n], 0, 0, 0);
        }
    }

    float inv[4];
#pragma unroll
    for (int r = 0; r < 4; ++r) inv[r] = 1.0f / sum[r];
#pragma unroll
    for (int n = 0; n < 4; ++n)
#pragma unroll
        for (int r = 0; r < 4; ++r) {
            int orow = q0 + wave * 16 + quad * 4 + r;
            size_t oidx = ((size_t)(b * 1024 + orow)) * 1024 + h * 64 + n * 16 + lm;
            Og[oidx] = f2b(o[n][r] * inv[r]);
        }
}

// ---- proj GEMM: out[M,N] = attn[M,K] * w2b[N,K]^T + b2, f32 out ----
__global__ void __launch_bounds__(256) gemm_proj(
    const unsigned short* __restrict__ A,   // attn [8192,1024] bf16
    const unsigned short* __restrict__ W,   // w2b [1024,1024] bf16
    const float* __restrict__ bias,         // [1024] f32
    float* __restrict__ Out)                // [8192,1024] f32
{
    const int K = 1024;
    int n0 = blockIdx.x * BN;
    int m0 = blockIdx.y * BM;
    int tid = threadIdx.x;
    int wave = tid >> 6, lane = tid & 63;
    int lm = lane & 15, quad = lane >> 4;
    int mblk = (wave & 1) * 64, nblk = (wave >> 1) * 64;

    __shared__ unsigned short As[BM * BK];
    __shared__ unsigned short Bs[BN * BK];

    int c0 = wave * 2;
    int lrow = c0 * 16 + (lane >> 2);
    int gcc = (lane & 3) ^ ((lane >> 3) & 3);
    const unsigned short* ga0 = A + (size_t)(m0 + lrow) * K + gcc * 8;
    const unsigned short* ga1 = A + (size_t)(m0 + lrow + 16) * K + gcc * 8;
    const unsigned short* gb0 = W + (size_t)(n0 + lrow) * K + gcc * 8;
    const unsigned short* gb1 = W + (size_t)(n0 + lrow + 16) * K + gcc * 8;
    unsigned short* la0 = As + c0 * 512;
    unsigned short* la1 = As + c0 * 512 + 512;
    unsigned short* lb0 = Bs + c0 * 512;
    unsigned short* lb1 = Bs + c0 * 512 + 512;

    int sa = (lm >> 1) & 3;
    int fro = lm * 32 + ((quad ^ sa) << 3);

    f32x4 acc[4][4];
#pragma unroll
    for (int i = 0; i < 4; ++i)
#pragma unroll
        for (int j = 0; j < 4; ++j)
            acc[i][j] = (f32x4){0.f, 0.f, 0.f, 0.f};

    for (int k0 = 0; k0 < K; k0 += BK) {
        __syncthreads();
        gld16(ga0 + k0, la0);
        gld16(ga1 + k0, la1);
        gld16(gb0 + k0, lb0);
        gld16(gb1 + k0, lb1);
        __syncthreads();
        bf16x8 af[4], bfr[4];
#pragma unroll
        for (int i = 0; i < 4; ++i)
            af[i] = *(const bf16x8*)(As + (mblk + i * 16) * 32 + fro);
#pragma unroll
        for (int j = 0; j < 4; ++j)
            bfr[j] = *(const bf16x8*)(Bs + (nblk + j * 16) * 32 + fro);
#pragma unroll
        for (int i = 0; i < 4; ++i)
#pragma unroll
            for (int j = 0; j < 4; ++j)
                acc[i][j] = __builtin_amdgcn_mfma_f32_16x16x32_bf16(af[i], bfr[j], acc[i][j], 0, 0, 0);
    }

#pragma unroll
    for (int j = 0; j < 4; ++j) {
        int n = n0 + nblk + j * 16 + lm;
        float bv = bias[n];
#pragma unroll
        for (int i = 0; i < 4; ++i) {
#pragma unroll
            for (int r = 0; r < 4; ++r) {
                int m = m0 + mblk + i * 16 + quad * 4 + r;
                Out[(size_t)m * 1024 + n] = acc[i][j][r] + bv;
            }
        }
    }
}

extern "C" void kernel_launch(void* const* d_in, const int* in_sizes, int n_in,
                              void* d_out, int out_size, void* d_ws, size_t ws_size,
                              hipStream_t stream) {
    const float* x  = (const float*)d_in[0];  // [8,1024,1024] f32
    const float* w1 = (const float*)d_in[1];  // [3072,1024] f32
    const float* b1 = (const float*)d_in[2];  // [3072] f32
    const float* w2 = (const float*)d_in[3];  // [1024,1024] f32
    const float* b2 = (const float*)d_in[4];  // [1024] f32
    float* out = (float*)d_out;               // [8192,1024] f32

    // ws (56 MiB peak):
    //  [0,16Mi)   xb (bf16 x)     -> overlaid by attn after gemm_qkv
    //  [16,22Mi)  w1b             -> dead after gemm_qkv
    //  [22,24Mi)  w2b
    //  [24,40Mi)  q   [40,56Mi) k
    //  v lives in d_out's first 16 MiB (dead before gemm_proj writes out)
    char* ws = (char*)d_ws;
    const size_t MB = 1024 * 1024;
    unsigned short* xb   = (unsigned short*)(ws);
    unsigned short* w1b  = (unsigned short*)(ws + 16 * MB);
    unsigned short* w2b  = (unsigned short*)(ws + 22 * MB);
    unsigned short* q    = (unsigned short*)(ws + 24 * MB);
    unsigned short* k    = (unsigned short*)(ws + 40 * MB);
    unsigned short* v    = (unsigned short*)d_out;
    unsigned short* attn = (unsigned short*)(ws);

    dim3 blk(256);
    cast_inputs<<<3072, blk, 0, stream>>>(
        (const float4*)x, (const float4*)w1, (const float4*)w2,
        (uint2*)xb, (uint2*)w1b, (uint2*)w2b);
    gemm_qkv<<<dim3(24, 64), blk, 0, stream>>>(xb, w1b, b1, q, k, v);
    attn_local<<<dim3(2048), blk, 0, stream>>>(q, k, v, attn);
    gemm_proj<<<dim3(8, 64), blk, 0, stream>>>(attn, w2b, b2, out);
}

// Round 7
// 210.849 us; speedup vs baseline: 4.3338x; 1.0713x over previous
//
#include <hip/hip_runtime.h>
#include <hip/hip_bf16.h>
#include <stdint.h>

// Problem: B=8, L=1024, C=1024, H=16, HD=64, window +/-64 (WS=128).
// Model (confirmed): inputs f32, output f32, bf16 intermediates.
// Round-7: BK=64 GEMMs — 32 MFMA per barrier pair (was 16), 8-chunk XOR
// swizzle (row stride 128B = bank wrap) keeps LDS reads conflict-free.

typedef __attribute__((ext_vector_type(8))) short bf16x8;
typedef __attribute__((ext_vector_type(4))) float f32x4;

__device__ inline unsigned short f2b(float f) {
    __hip_bfloat16 h = __float2bfloat16(f);
    return *reinterpret_cast<unsigned short*>(&h);
}

// async global->LDS, 16B per lane; LDS dest = wave-uniform base + lane*16
__device__ inline void gld16(const unsigned short* g, unsigned short* l) {
    __builtin_amdgcn_global_load_lds(
        (const __attribute__((address_space(1))) void*)g,
        (__attribute__((address_space(3))) void*)l, 16, 0, 0);
}

#define BM 128
#define BN 128
#define BK 64

// ---- cast f32 inputs to bf16 side buffers (x, in_proj_w, out_w) ----
__global__ void __launch_bounds__(256) cast_inputs(
    const float4* __restrict__ x, const float4* __restrict__ w1,
    const float4* __restrict__ w2,
    uint2* __restrict__ xb, uint2* __restrict__ w1b, uint2* __restrict__ w2b)
{
    const int N0 = 2097152, N1 = 786432, N2 = 262144;  // float4 counts
    int stride = gridDim.x * blockDim.x;
    for (int i = blockIdx.x * blockDim.x + threadIdx.x; i < N0 + N1 + N2; i += stride) {
        const float4* src; uint2* dst; int idx;
        if (i < N0)            { src = x;  dst = xb;  idx = i; }
        else if (i < N0 + N1)  { src = w1; dst = w1b; idx = i - N0; }
        else                   { src = w2; dst = w2b; idx = i - N0 - N1; }
        float4 f = src[idx];
        unsigned short t[4] = {f2b(f.x), f2b(f.y), f2b(f.z), f2b(f.w)};
        dst[idx] = *(uint2*)t;
    }
}

// ---- QKV GEMM: C[M,N] = xb[M,K] * w1b[N,K]^T + b1 ; scatter to Q/K/V ----
// 128x64 bf16 LDS tiles, unpadded. Row stride 64 elem = 128 B = exact bank
// wrap, so chunk c of row r is stored at c ^ (r&7). DMA side: lane l covers
// (row_in_8 = l>>3, stored chunk = l&7) -> global logical chunk (l&7)^(l>>3).
// Read side: logical chunk (half*4+quad) -> stored (half*4+quad)^(lm&7):
// 8 distinct 16B groups, 2 lanes each (lm and lm+8) = conflict-free.
__global__ void __launch_bounds__(256) gemm_qkv(
    const unsigned short* __restrict__ A,   // xb [8192,1024] bf16
    const unsigned short* __restrict__ W,   // w1b [3072,1024] bf16
    const float* __restrict__ bias,         // [3072] f32
    unsigned short* __restrict__ Qo,
    unsigned short* __restrict__ Ko,
    unsigned short* __restrict__ Vo)
{
    const int K = 1024;
    int n0 = blockIdx.x * BN;
    int m0 = blockIdx.y * BM;
    int tid = threadIdx.x;
    int wave = tid >> 6, lane = tid & 63;
    int lm = lane & 15, quad = lane >> 4;
    int mblk = (wave & 1) * 64, nblk = (wave >> 1) * 64;

    __shared__ unsigned short As[BM * BK];  // 16 KiB
    __shared__ unsigned short Bs[BN * BK];  // 16 KiB

    int drow = lane >> 3;               // 0..7 row within an 8-row DMA chunk
    int gcc  = (lane & 7) ^ drow;       // swizzled logical col-chunk (x8 elems)
    // wave stages A rows [wave*32,+32) and B rows [wave*32,+32), 4 DMAs each
    const unsigned short* ga[4]; const unsigned short* gb[4];
    unsigned short *la[4], *lb[4];
#pragma unroll
    for (int p = 0; p < 4; ++p) {
        int r = wave * 32 + p * 8 + drow;
        ga[p] = A + (size_t)(m0 + r) * K + gcc * 8;
        gb[p] = W + (size_t)(n0 + r) * K + gcc * 8;
        la[p] = As + (wave * 32 + p * 8) * 64;
        lb[p] = Bs + (wave * 32 + p * 8) * 64;
    }
    int lm7 = lm & 7;

    f32x4 acc[4][4];
#pragma unroll
    for (int i = 0; i < 4; ++i)
#pragma unroll
        for (int j = 0; j < 4; ++j)
            acc[i][j] = (f32x4){0.f, 0.f, 0.f, 0.f};

    for (int k0 = 0; k0 < K; k0 += BK) {
        __syncthreads();                 // prev iter's ds_reads done
#pragma unroll
        for (int p = 0; p < 4; ++p) gld16(ga[p] + k0, la[p]);
#pragma unroll
        for (int p = 0; p < 4; ++p) gld16(gb[p] + k0, lb[p]);
        __syncthreads();                 // DMA drained
        bf16x8 af[4][2], bfr[4][2];
#pragma unroll
        for (int i = 0; i < 4; ++i)
#pragma unroll
            for (int hhh = 0; hhh < 2; ++hhh)
                af[i][hhh] = *(const bf16x8*)(As + (mblk + i * 16 + lm) * 64 +
                                              (((hhh * 4 + quad) ^ lm7) << 3));
#pragma unroll
        for (int j = 0; j < 4; ++j)
#pragma unroll
            for (int hhh = 0; hhh < 2; ++hhh)
                bfr[j][hhh] = *(const bf16x8*)(Bs + (nblk + j * 16 + lm) * 64 +
                                               (((hhh * 4 + quad) ^ lm7) << 3));
#pragma unroll
        for (int i = 0; i < 4; ++i)
#pragma unroll
            for (int j = 0; j < 4; ++j) {
                acc[i][j] = __builtin_amdgcn_mfma_f32_16x16x32_bf16(af[i][0], bfr[j][0], acc[i][j], 0, 0, 0);
                acc[i][j] = __builtin_amdgcn_mfma_f32_16x16x32_bf16(af[i][1], bfr[j][1], acc[i][j], 0, 0, 0);
            }
    }

#pragma unroll
    for (int j = 0; j < 4; ++j) {
        int n = n0 + nblk + j * 16 + lm;
        float bv = bias[n];
        int sec = n >> 10, rem = n & 1023;
        int h = rem >> 6, d = rem & 63;
        unsigned short* dst = (sec == 0) ? Qo : (sec == 1) ? Ko : Vo;
#pragma unroll
        for (int i = 0; i < 4; ++i) {
#pragma unroll
            for (int r = 0; r < 4; ++r) {
                int m = m0 + mblk + i * 16 + quad * 4 + r;
                int bb = m >> 10, sl = m & 1023;
                size_t idx = ((size_t)((bb * 16 + h) * 1024 + sl)) * 64 + d;
                dst[idx] = f2b(acc[i][j][r] + bv);
            }
        }
    }
}

// ---- local attention (unchanged) ----
__global__ void __launch_bounds__(256) attn_local(
    const unsigned short* __restrict__ Qg,   // [B*H,1024,64] bf16
    const unsigned short* __restrict__ Kg,
    const unsigned short* __restrict__ Vg,
    unsigned short* __restrict__ Og)         // [8192,1024] bf16
{
    const int KP = 72;
    const int VP = 200;
    __shared__ unsigned short Ks[192 * KP];
    __shared__ unsigned short Vt[64 * VP];

    int tid = threadIdx.x;
    int wave = tid >> 6, lane = tid & 63;
    int lm = lane & 15, quad = lane >> 4;

    int bh = blockIdx.x >> 4;
    int qt = blockIdx.x & 15;
    int q0 = qt * 64;
    int b = bh >> 4, h = bh & 15;
    const unsigned short* Qbh = Qg + (size_t)bh * 1024 * 64;
    const unsigned short* Kbh = Kg + (size_t)bh * 1024 * 64;
    const unsigned short* Vbh = Vg + (size_t)bh * 1024 * 64;
    int j0 = q0 - 64;

#pragma unroll
    for (int it = 0; it < 6; ++it) {
        int id = it * 256 + tid;
        int r = id >> 3;
        int c = (id & 7) * 8;
        int j = j0 + r;
        uint4 kv, vv;
        kv.x = kv.y = kv.z = kv.w = 0;
        vv = kv;
        if (j >= 0 && j < 1024) {
            kv = *(const uint4*)(Kbh + (size_t)j * 64 + c);
            vv = *(const uint4*)(Vbh + (size_t)j * 64 + c);
        }
        *(uint4*)(Ks + r * KP + c) = kv;
        unsigned short tmp[8];
        *(uint4*)tmp = vv;
#pragma unroll
        for (int e = 0; e < 8; ++e) Vt[(c + e) * VP + r] = tmp[e];
    }
    __syncthreads();

    int qrow = q0 + wave * 16;
    bf16x8 qf0 = *(const bf16x8*)(Qbh + (size_t)(qrow + lm) * 64 + quad * 8);
    bf16x8 qf1 = *(const bf16x8*)(Qbh + (size_t)(qrow + lm) * 64 + 32 + quad * 8);

    f32x4 sc[12];
#pragma unroll
    for (int kt = 0; kt < 12; ++kt) {
        f32x4 a = (f32x4){0.f, 0.f, 0.f, 0.f};
        bf16x8 k0f = *(const bf16x8*)(Ks + (kt * 16 + lm) * KP + quad * 8);
        bf16x8 k1f = *(const bf16x8*)(Ks + (kt * 16 + lm) * KP + 32 + quad * 8);
        a = __builtin_amdgcn_mfma_f32_16x16x32_bf16(qf0, k0f, a, 0, 0, 0);
        a = __builtin_amdgcn_mfma_f32_16x16x32_bf16(qf1, k1f, a, 0, 0, 0);
        sc[kt] = a;
    }

    float mx[4] = {-3e38f, -3e38f, -3e38f, -3e38f};
#pragma unroll
    for (int kt = 0; kt < 12; ++kt) {
        int jg = j0 + kt * 16 + lm;
#pragma unroll
        for (int r = 0; r < 4; ++r) {
            int irow = q0 + wave * 16 + quad * 4 + r;
            int diff = irow - jg;
            bool ok = (jg >= 0) && (jg < 1024) && (diff <= 64) && (diff >= -64);
            float s = ok ? sc[kt][r] * 0.125f : -30000.0f;
            sc[kt][r] = s;
            mx[r] = fmaxf(mx[r], s);
        }
    }
#pragma unroll
    for (int off = 1; off <= 8; off <<= 1)
#pragma unroll
        for (int r = 0; r < 4; ++r)
            mx[r] = fmaxf(mx[r], __shfl_xor(mx[r], off, 64));

    float sum[4] = {0.f, 0.f, 0.f, 0.f};
#pragma unroll
    for (int kt = 0; kt < 12; ++kt)
#pragma unroll
        for (int r = 0; r < 4; ++r) {
            float p = __expf(sc[kt][r] - mx[r]);
            sc[kt][r] = p;
            sum[r] += p;
        }
#pragma unroll
    for (int off = 1; off <= 8; off <<= 1)
#pragma unroll
        for (int r = 0; r < 4; ++r)
            sum[r] += __shfl_xor(sum[r], off, 64);

    __syncthreads();
    unsigned short* Pb = Ks + wave * 3200;
#pragma unroll
    for (int kt = 0; kt < 12; ++kt)
#pragma unroll
        for (int r = 0; r < 4; ++r)
            Pb[(quad * 4 + r) * VP + kt * 16 + lm] = f2b(sc[kt][r]);
    __syncthreads();

    f32x4 o[4];
#pragma unroll
    for (int n = 0; n < 4; ++n) o[n] = (f32x4){0.f, 0.f, 0.f, 0.f};
#pragma unroll
    for (int jc = 0; jc < 6; ++jc) {
        bf16x8 pf = *(const bf16x8*)(Pb + lm * VP + jc * 32 + quad * 8);
#pragma unroll
        for (int n = 0; n < 4; ++n) {
            bf16x8 vf = *(const bf16x8*)(Vt + (n * 16 + lm) * VP + jc * 32 + quad * 8);
            o[n] = __builtin_amdgcn_mfma_f32_16x16x32_bf16(pf, vf, o[n], 0, 0, 0);
        }
    }

    float inv[4];
#pragma unroll
    for (int r = 0; r < 4; ++r) inv[r] = 1.0f / sum[r];
#pragma unroll
    for (int n = 0; n < 4; ++n)
#pragma unroll
        for (int r = 0; r < 4; ++r) {
            int orow = q0 + wave * 16 + quad * 4 + r;
            size_t oidx = ((size_t)(b * 1024 + orow)) * 1024 + h * 64 + n * 16 + lm;
            Og[oidx] = f2b(o[n][r] * inv[r]);
        }
}

// ---- proj GEMM: out[M,N] = attn[M,K] * w2b[N,K]^T + b2, f32 out ----
__global__ void __launch_bounds__(256) gemm_proj(
    const unsigned short* __restrict__ A,   // attn [8192,1024] bf16
    const unsigned short* __restrict__ W,   // w2b [1024,1024] bf16
    const float* __restrict__ bias,         // [1024] f32
    float* __restrict__ Out)                // [8192,1024] f32
{
    const int K = 1024;
    int n0 = blockIdx.x * BN;
    int m0 = blockIdx.y * BM;
    int tid = threadIdx.x;
    int wave = tid >> 6, lane = tid & 63;
    int lm = lane & 15, quad = lane >> 4;
    int mblk = (wave & 1) * 64, nblk = (wave >> 1) * 64;

    __shared__ unsigned short As[BM * BK];
    __shared__ unsigned short Bs[BN * BK];

    int drow = lane >> 3;
    int gcc  = (lane & 7) ^ drow;
    const unsigned short* ga[4]; const unsigned short* gb[4];
    unsigned short *la[4], *lb[4];
#pragma unroll
    for (int p = 0; p < 4; ++p) {
        int r = wave * 32 + p * 8 + drow;
        ga[p] = A + (size_t)(m0 + r) * K + gcc * 8;
        gb[p] = W + (size_t)(n0 + r) * K + gcc * 8;
        la[p] = As + (wave * 32 + p * 8) * 64;
        lb[p] = Bs + (wave * 32 + p * 8) * 64;
    }
    int lm7 = lm & 7;

    f32x4 acc[4][4];
#pragma unroll
    for (int i = 0; i < 4; ++i)
#pragma unroll
        for (int j = 0; j < 4; ++j)
            acc[i][j] = (f32x4){0.f, 0.f, 0.f, 0.f};

    for (int k0 = 0; k0 < K; k0 += BK) {
        __syncthreads();
#pragma unroll
        for (int p = 0; p < 4; ++p) gld16(ga[p] + k0, la[p]);
#pragma unroll
        for (int p = 0; p < 4; ++p) gld16(gb[p] + k0, lb[p]);
        __syncthreads();
        bf16x8 af[4][2], bfr[4][2];
#pragma unroll
        for (int i = 0; i < 4; ++i)
#pragma unroll
            for (int hhh = 0; hhh < 2; ++hhh)
                af[i][hhh] = *(const bf16x8*)(As + (mblk + i * 16 + lm) * 64 +
                                              (((hhh * 4 + quad) ^ lm7) << 3));
#pragma unroll
        for (int j = 0; j < 4; ++j)
#pragma unroll
            for (int hhh = 0; hhh < 2; ++hhh)
                bfr[j][hhh] = *(const bf16x8*)(Bs + (nblk + j * 16 + lm) * 64 +
                                               (((hhh * 4 + quad) ^ lm7) << 3));
#pragma unroll
        for (int i = 0; i < 4; ++i)
#pragma unroll
            for (int j = 0; j < 4; ++j) {
                acc[i][j] = __builtin_amdgcn_mfma_f32_16x16x32_bf16(af[i][0], bfr[j][0], acc[i][j], 0, 0, 0);
                acc[i][j] = __builtin_amdgcn_mfma_f32_16x16x32_bf16(af[i][1], bfr[j][1], acc[i][j], 0, 0, 0);
            }
    }

#pragma unroll
    for (int j = 0; j < 4; ++j) {
        int n = n0 + nblk + j * 16 + lm;
        float bv = bias[n];
#pragma unroll
        for (int i = 0; i < 4; ++i) {
#pragma unroll
            for (int r = 0; r < 4; ++r) {
                int m = m0 + mblk + i * 16 + quad * 4 + r;
                Out[(size_t)m * 1024 + n] = acc[i][j][r] + bv;
            }
        }
    }
}

extern "C" void kernel_launch(void* const* d_in, const int* in_sizes, int n_in,
                              void* d_out, int out_size, void* d_ws, size_t ws_size,
                              hipStream_t stream) {
    const float* x  = (const float*)d_in[0];  // [8,1024,1024] f32
    const float* w1 = (const float*)d_in[1];  // [3072,1024] f32
    const float* b1 = (const float*)d_in[2];  // [3072] f32
    const float* w2 = (const float*)d_in[3];  // [1024,1024] f32
    const float* b2 = (const float*)d_in[4];  // [1024] f32
    float* out = (float*)d_out;               // [8192,1024] f32

    // ws (56 MiB peak):
    //  [0,16Mi)   xb  -> overlaid by attn after gemm_qkv
    //  [16,22Mi)  w1b -> dead after gemm_qkv
    //  [22,24Mi)  w2b
    //  [24,40Mi)  q   [40,56Mi) k
    //  v lives in d_out's first 16 MiB (dead before gemm_proj writes out)
    char* ws = (char*)d_ws;
    const size_t MB = 1024 * 1024;
    unsigned short* xb   = (unsigned short*)(ws);
    unsigned short* w1b  = (unsigned short*)(ws + 16 * MB);
    unsigned short* w2b  = (unsigned short*)(ws + 22 * MB);
    unsigned short* q    = (unsigned short*)(ws + 24 * MB);
    unsigned short* k    = (unsigned short*)(ws + 40 * MB);
    unsigned short* v    = (unsigned short*)d_out;
    unsigned short* attn = (unsigned short*)(ws);

    dim3 blk(256);
    cast_inputs<<<3072, blk, 0, stream>>>(
        (const float4*)x, (const float4*)w1, (const float4*)w2,
        (uint2*)xb, (uint2*)w1b, (uint2*)w2b);
    gemm_qkv<<<dim3(24, 64), blk, 0, stream>>>(xb, w1b, b1, q, k, v);
    attn_local<<<dim3(2048), blk, 0, stream>>>(q, k, v, attn);
    gemm_proj<<<dim3(8, 64), blk, 0, stream>>>(attn, w2b, b2, out);
}